// Round 1
// baseline (811.870 us; speedup 1.0000x reference)
//
#include <hip/hip_runtime.h>
#include <hip/hip_bf16.h>

// GNN: h = x@We^T + be; 2x { h = relu(segsum(h[col],row) @ W^T + b) };
// out = relu(mean(h,1) @ Wc1^T + bc1) @ Wc2^T + bc2   (scalar fp32)
//
// Restructure: relu((A h) W^T + b) == relu(A (h W^T) + b)  (A = sparse adj).
// Dense GEMMs in bf16 MFMA (m97-style 128x128 tile, global_load_lds w=16),
// aggregation as CSR gather + fp32 accumulate + bias + relu -> bf16.

#define N_NODES 4096
#define IN_DIM_ 512
#define HID_ 4096
#define NEDGE 65536

typedef __bf16 bf16x8 __attribute__((ext_vector_type(8)));
typedef float f32x4 __attribute__((ext_vector_type(4)));
typedef unsigned short u16x8 __attribute__((ext_vector_type(8)));

__device__ __forceinline__ unsigned short f2bf(float f) {
  unsigned u = __float_as_uint(f);
  return (unsigned short)((u + 0x7fffu + ((u >> 16) & 1u)) >> 16);  // RNE
}
__device__ __forceinline__ float bf2f(unsigned short h) {
  return __uint_as_float((unsigned)h << 16);
}

// ---------------- fp32 -> bf16, 8 elems/thread ----------------
__global__ __launch_bounds__(256) void cvt_bf16(const float* __restrict__ in,
                                                unsigned short* __restrict__ out,
                                                int n) {
  int i = (blockIdx.x * 256 + threadIdx.x) * 8;
  if (i >= n) return;
  const float4 a = *(const float4*)(in + i);
  const float4 b = *(const float4*)(in + i + 4);
  u16x8 r;
  r[0] = f2bf(a.x); r[1] = f2bf(a.y); r[2] = f2bf(a.z); r[3] = f2bf(a.w);
  r[4] = f2bf(b.x); r[5] = f2bf(b.y); r[6] = f2bf(b.z); r[7] = f2bf(b.w);
  *(u16x8*)(out + i) = r;
}

// ---------------- CSR build ----------------
__global__ __launch_bounds__(256) void zero_i32(int* __restrict__ p, int n) {
  int i = blockIdx.x * 256 + threadIdx.x;
  if (i < n) p[i] = 0;
}

__global__ __launch_bounds__(256) void hist_rows(const int* __restrict__ row,
                                                 int* __restrict__ counts) {
  int e = blockIdx.x * 256 + threadIdx.x;
  if (e < NEDGE) atomicAdd(&counts[row[e]], 1);
}

// exclusive scan of counts[4096] -> starts[4097]; single block of 1024 threads
__global__ __launch_bounds__(1024) void scan4096(const int* __restrict__ counts,
                                                 int* __restrict__ starts) {
  __shared__ int sa[1024], sb[1024];
  const int t = threadIdx.x;
  const int c0 = counts[t * 4], c1 = counts[t * 4 + 1],
            c2 = counts[t * 4 + 2], c3 = counts[t * 4 + 3];
  const int local = c0 + c1 + c2 + c3;
  sa[t] = local;
  __syncthreads();
  int* src = sa; int* dst = sb;
  for (int off = 1; off < 1024; off <<= 1) {
    int v = src[t];
    if (t >= off) v += src[t - off];
    dst[t] = v;
    __syncthreads();
    int* tmp = src; src = dst; dst = tmp;
  }
  const int excl = (t == 0) ? 0 : src[t - 1];
  starts[t * 4]     = excl;
  starts[t * 4 + 1] = excl + c0;
  starts[t * 4 + 2] = excl + c0 + c1;
  starts[t * 4 + 3] = excl + c0 + c1 + c2;
  if (t == 1023) starts[4096] = excl + local;
}

__global__ __launch_bounds__(256) void fill_adj(const int* __restrict__ row,
                                                const int* __restrict__ col,
                                                const int* __restrict__ starts,
                                                int* __restrict__ cursor,
                                                int* __restrict__ adj) {
  int e = blockIdx.x * 256 + threadIdx.x;
  if (e >= NEDGE) return;
  int r = row[e];
  int p = atomicAdd(&cursor[r], 1);
  adj[starts[r] + p] = col[e];
}

// ---------------- bf16 GEMM: C[M,N] = A[M,K] @ B[N,K]^T (+bias) ----------------
// m97 structure: 128x128 tile, BK=32, 4 waves each 64x64 (4x4 of 16x16x32 MFMA),
// global_load_lds width=16, 2-barrier K-loop.
__global__ __launch_bounds__(256) void gemm_bt(const unsigned short* __restrict__ A,
                                               const unsigned short* __restrict__ B,
                                               unsigned short* __restrict__ C,
                                               int M, int N, int K,
                                               const float* __restrict__ bias) {
  __shared__ unsigned short As[128 * 32];  // [m][k], row stride 32 elems (64 B)
  __shared__ unsigned short Bs[128 * 32];  // [n][k]
  const int t = threadIdx.x;
  const int bm = blockIdx.x * 128, bn = blockIdx.y * 128;
  const int wave = t >> 6, lane = t & 63;
  const int wm = (wave >> 1) * 64, wn = (wave & 1) * 64;
  const int m16 = lane & 15, quad = lane >> 4;

  f32x4 acc[4][4] = {};

  // staging: thread t loads 16 B; instr0 covers rows 0..63, instr1 rows 64..127
  const int srow = t >> 2;          // 0..63
  const int scol = (t & 3) * 8;     // 0,8,16,24 (elems)
  const unsigned short* Ag0 = A + (size_t)(bm + srow) * K + scol;
  const unsigned short* Ag1 = A + (size_t)(bm + 64 + srow) * K + scol;
  const unsigned short* Bg0 = B + (size_t)(bn + srow) * K + scol;
  const unsigned short* Bg1 = B + (size_t)(bn + 64 + srow) * K + scol;
  char* AsB = (char*)As;
  char* BsB = (char*)Bs;
  char* lA0 = AsB + t * 16;
  char* lA1 = AsB + 4096 + t * 16;
  char* lB0 = BsB + t * 16;
  char* lB1 = BsB + 4096 + t * 16;

  for (int kb = 0; kb < K; kb += 32) {
    __builtin_amdgcn_global_load_lds(
        (const __attribute__((address_space(1))) void*)(Ag0 + kb),
        (__attribute__((address_space(3))) void*)lA0, 16, 0, 0);
    __builtin_amdgcn_global_load_lds(
        (const __attribute__((address_space(1))) void*)(Ag1 + kb),
        (__attribute__((address_space(3))) void*)lA1, 16, 0, 0);
    __builtin_amdgcn_global_load_lds(
        (const __attribute__((address_space(1))) void*)(Bg0 + kb),
        (__attribute__((address_space(3))) void*)lB0, 16, 0, 0);
    __builtin_amdgcn_global_load_lds(
        (const __attribute__((address_space(1))) void*)(Bg1 + kb),
        (__attribute__((address_space(3))) void*)lB1, 16, 0, 0);
    __syncthreads();  // drains vmcnt -> LDS visible

    bf16x8 af[4], bfr[4];
#pragma unroll
    for (int r = 0; r < 4; ++r)
      af[r] = *(const bf16x8*)(AsB + (wm + r * 16 + m16) * 64 + quad * 16);
#pragma unroll
    for (int c = 0; c < 4; ++c)
      bfr[c] = *(const bf16x8*)(BsB + (wn + c * 16 + m16) * 64 + quad * 16);
#pragma unroll
    for (int r = 0; r < 4; ++r)
#pragma unroll
      for (int c = 0; c < 4; ++c)
        acc[r][c] = __builtin_amdgcn_mfma_f32_16x16x32_bf16(af[r], bfr[c],
                                                            acc[r][c], 0, 0, 0);
    __syncthreads();  // before next stage overwrites LDS
  }

  // C/D layout (verified m89/m91): col = lane&15, row = quad*4 + reg
#pragma unroll
  for (int r = 0; r < 4; ++r) {
#pragma unroll
    for (int c = 0; c < 4; ++c) {
      const int row0 = bm + wm + r * 16 + quad * 4;
      const int col = bn + wn + c * 16 + m16;
      const float bv = bias ? bias[col] : 0.0f;
#pragma unroll
      for (int i = 0; i < 4; ++i) {
        float v = acc[r][c][i] + bv;
        C[(size_t)(row0 + i) * N + col] = f2bf(v);
      }
    }
  }
}

// ---------------- aggregation: h[node] = relu(sum_{c in adj(node)} g[c] + b) ----------------
// grid (2, N_NODES): 2048 feats per block, 8 per thread, fp32 accumulate
__global__ __launch_bounds__(256) void aggr_bias_relu(
    const unsigned short* __restrict__ g, const int* __restrict__ starts,
    const int* __restrict__ adj, const float* __restrict__ bias,
    unsigned short* __restrict__ hout) {
  const int node = blockIdx.y;
  const int f0 = blockIdx.x * 2048 + threadIdx.x * 8;
  float acc[8] = {0, 0, 0, 0, 0, 0, 0, 0};
  const int s = starts[node], e = starts[node + 1];
  for (int j = s; j < e; ++j) {
    const int c = adj[j];
    u16x8 v = *(const u16x8*)(g + (size_t)c * HID_ + f0);
#pragma unroll
    for (int i = 0; i < 8; ++i) acc[i] += bf2f(v[i]);
  }
  const float4 b0 = *(const float4*)(bias + f0);
  const float4 b1 = *(const float4*)(bias + f0 + 4);
  const float bb[8] = {b0.x, b0.y, b0.z, b0.w, b1.x, b1.y, b1.z, b1.w};
  u16x8 r;
#pragma unroll
  for (int i = 0; i < 8; ++i) r[i] = f2bf(fmaxf(acc[i] + bb[i], 0.0f));
  *(u16x8*)(hout + (size_t)node * HID_ + f0) = r;
}

// ---------------- hm[row] = mean(h[row,:]) ----------------
__global__ __launch_bounds__(256) void row_mean(const unsigned short* __restrict__ h,
                                                float* __restrict__ hm) {
  const int row = blockIdx.x, t = threadIdx.x;
  const u16x8* p = (const u16x8*)(h + (size_t)row * HID_);
  u16x8 v1 = p[t], v2 = p[t + 256];
  float s = 0.f;
#pragma unroll
  for (int i = 0; i < 8; ++i) s += bf2f(v1[i]) + bf2f(v2[i]);
  for (int off = 32; off > 0; off >>= 1) s += __shfl_down(s, off);
  __shared__ float ws[4];
  if ((t & 63) == 0) ws[t >> 6] = s;
  __syncthreads();
  if (t == 0) hm[row] = (ws[0] + ws[1] + ws[2] + ws[3]) * (1.0f / (float)HID_);
}

// ---------------- z[j] = relu(Wc1[j,:].hm + bc1[j]), one wave per j ----------------
__global__ __launch_bounds__(256) void clf1(const float* __restrict__ Wc1,
                                            const float* __restrict__ bc1,
                                            const float* __restrict__ hm,
                                            float* __restrict__ z) {
  const int wave = threadIdx.x >> 6, lane = threadIdx.x & 63;
  const int j = blockIdx.x * 4 + wave;
  const float* w = Wc1 + (size_t)j * HID_;
  float s = 0.f;
  for (int i = lane; i < HID_; i += 64) s += w[i] * hm[i];
  for (int off = 32; off > 0; off >>= 1) s += __shfl_down(s, off);
  if (lane == 0) z[j] = fmaxf(s + bc1[j], 0.0f);
}

// ---------------- out = Wc2.z + bc2 ----------------
__global__ __launch_bounds__(256) void clf2(const float* __restrict__ Wc2,
                                            const float* __restrict__ bc2,
                                            const float* __restrict__ z,
                                            float* __restrict__ out) {
  const int t = threadIdx.x;
  float s = 0.f;
  for (int i = t; i < HID_ / 2; i += 256) s += z[i] * Wc2[i];
  for (int off = 32; off > 0; off >>= 1) s += __shfl_down(s, off);
  __shared__ float ws[4];
  if ((t & 63) == 0) ws[t >> 6] = s;
  __syncthreads();
  if (t == 0) out[0] = ws[0] + ws[1] + ws[2] + ws[3] + bc2[0];
}

extern "C" void kernel_launch(void* const* d_in, const int* in_sizes, int n_in,
                              void* d_out, int out_size, void* d_ws, size_t ws_size,
                              hipStream_t stream) {
  (void)in_sizes; (void)n_in; (void)out_size; (void)ws_size;
  const float* x       = (const float*)d_in[0];
  const int*   edge    = (const int*)d_in[1];
  const int*   row     = edge;
  const int*   col     = edge + NEDGE;
  const float* W_embed = (const float*)d_in[2];
  const float* b_embed = (const float*)d_in[3];
  const float* W1      = (const float*)d_in[4];
  const float* b1      = (const float*)d_in[5];
  const float* W2      = (const float*)d_in[6];
  const float* b2      = (const float*)d_in[7];
  const float* Wc1     = (const float*)d_in[8];
  const float* bc1     = (const float*)d_in[9];
  const float* Wc2     = (const float*)d_in[10];
  const float* bc2     = (const float*)d_in[11];
  float* out = (float*)d_out;

  char* ws = (char*)d_ws;
  size_t off = 0;
  auto alloc = [&](size_t bytes) {
    char* p = ws + off;
    off += (bytes + 255) & ~(size_t)255;
    return p;
  };
  unsigned short* xb  = (unsigned short*)alloc((size_t)N_NODES * IN_DIM_ * 2);
  unsigned short* web = (unsigned short*)alloc((size_t)HID_ * IN_DIM_ * 2);
  unsigned short* w1b = (unsigned short*)alloc((size_t)HID_ * HID_ * 2);
  unsigned short* w2b = (unsigned short*)alloc((size_t)HID_ * HID_ * 2);
  unsigned short* h   = (unsigned short*)alloc((size_t)N_NODES * HID_ * 2);
  unsigned short* g   = (unsigned short*)alloc((size_t)N_NODES * HID_ * 2);
  int* counts = (int*)alloc(N_NODES * 4);
  int* cursor = (int*)alloc(N_NODES * 4);
  int* starts = (int*)alloc((N_NODES + 1) * 4);
  int* adj    = (int*)alloc(NEDGE * 4);
  float* hm   = (float*)alloc(N_NODES * 4);
  float* z    = (float*)alloc((HID_ / 2) * 4);

  // CSR build (ws is re-poisoned each call -> must zero)
  zero_i32<<<16, 256, 0, stream>>>(counts, N_NODES);
  zero_i32<<<16, 256, 0, stream>>>(cursor, N_NODES);
  hist_rows<<<NEDGE / 256, 256, 0, stream>>>(row, counts);
  scan4096<<<1, 1024, 0, stream>>>(counts, starts);
  fill_adj<<<NEDGE / 256, 256, 0, stream>>>(row, col, starts, cursor, adj);

  // fp32 -> bf16 inputs/weights
  cvt_bf16<<<(N_NODES * IN_DIM_ / 8) / 256, 256, 0, stream>>>(x, xb, N_NODES * IN_DIM_);
  cvt_bf16<<<(HID_ * IN_DIM_ / 8) / 256, 256, 0, stream>>>(W_embed, web, HID_ * IN_DIM_);
  cvt_bf16<<<(HID_ * HID_ / 8) / 256, 256, 0, stream>>>(W1, w1b, HID_ * HID_);
  cvt_bf16<<<(HID_ * HID_ / 8) / 256, 256, 0, stream>>>(W2, w2b, HID_ * HID_);

  // h = x @ We^T + be
  gemm_bt<<<dim3(32, 32), 256, 0, stream>>>(xb, web, h, N_NODES, HID_, IN_DIM_, b_embed);
  // layer 1: g = h @ W1^T ; h = relu(A g + b1)
  gemm_bt<<<dim3(32, 32), 256, 0, stream>>>(h, w1b, g, N_NODES, HID_, HID_, nullptr);
  aggr_bias_relu<<<dim3(2, N_NODES), 256, 0, stream>>>(g, starts, adj, b1, h);
  // layer 2
  gemm_bt<<<dim3(32, 32), 256, 0, stream>>>(h, w2b, g, N_NODES, HID_, HID_, nullptr);
  aggr_bias_relu<<<dim3(2, N_NODES), 256, 0, stream>>>(g, starts, adj, b2, h);
  // classifier tail
  row_mean<<<N_NODES, 256, 0, stream>>>(h, hm);
  clf1<<<(HID_ / 2) / 4, 256, 0, stream>>>(Wc1, bc1, hm, z);
  clf2<<<1, 256, 0, stream>>>(Wc2, bc2, z, out);
}